// Round 1
// baseline (124.924 us; speedup 1.0000x reference)
//
#include <hip/hip_runtime.h>
#include <hip/hip_bf16.h>
#include <stdint.h>

#define BATCH   32768
#define NBLK    8
#define BIN     256
#define BOUT    256
#define XCOLS   2048      // NBLK*BIN
#define BM      128
#define BK      64
#define KSTEPS  4         // BIN/BK

typedef short bf16x8_t __attribute__((ext_vector_type(8)));
typedef float f32x4_t  __attribute__((ext_vector_type(4)));

// ---------------- prepass: W fp32 [8][256][256] -> swizzled bf16 ws ----------------
// Wsz layout [n][kk][s=o*8+c][j=0..7] (16B slots). The main kernel copies this
// LINEARLY into LDS (global_load_lds), so the XOR swizzle is baked in here:
//   LDS slot (o, c) must hold k-run (c ^ (o&7))*8 of row o, K-tile kk.
__global__ __launch_bounds__(256) void prep_w_kernel(
    const float* __restrict__ W, unsigned short* __restrict__ Wsz) {
  int idx = blockIdx.x * 256 + threadIdx.x;   // 0 .. 2^19-1
  int j  = idx & 7;
  int s  = (idx >> 3) & 2047;
  int kk = (idx >> 14) & 3;
  int n  = idx >> 16;
  int o  = s >> 3;
  int c  = s & 7;
  int k  = kk * 64 + ((c ^ (o & 7)) * 8) + j;
  float v = W[((size_t)(n * 256 + o) * 256) + k];
  uint32_t bits = __builtin_bit_cast(uint32_t, v);
  // round-to-nearest-even
  Wsz[idx] = (unsigned short)((bits + 0x7FFFu + ((bits >> 16) & 1u)) >> 16);
}

// ---------------- main kernel ----------------
__global__ __launch_bounds__(256, 2) void blocklinear_kernel(
    const float* __restrict__ x, const unsigned short* __restrict__ Wsz,
    const float* __restrict__ bias, float* __restrict__ y) {
  // X tile staged as fp32 (converted to bf16 at fragment-read time).
  // 16B-slot XOR swizzle: slot ^= (row & 15)  [16 slots/row of 256B]
  __shared__ __align__(16) float          xs[BM * BK];      // 32 KB
  // W tile bf16, swizzle pre-baked by prepass: slot ^= (o & 7) [8 slots/row]
  __shared__ __align__(16) unsigned short ws[BOUT * BK];    // 32 KB

  const int wgid = blockIdx.x;
  const int n    = wgid & 7;        // block id fastest -> per-XCD W L2 affinity
  const int mt   = wgid >> 3;
  const int m0   = mt * BM;
  const int tid  = threadIdx.x;
  const int wave = tid >> 6;
  const int lane = tid & 63;
  const int fr   = lane & 15;
  const int fq   = lane >> 4;

  f32x4_t acc[8][4];
#pragma unroll
  for (int mf = 0; mf < 8; ++mf)
#pragma unroll
    for (int nf = 0; nf < 4; ++nf)
      acc[mf][nf] = (f32x4_t){0.f, 0.f, 0.f, 0.f};

  const float* xg = x + (size_t)m0 * XCOLS + n * BIN;
  const unsigned short* wbase = Wsz + (size_t)n * (KSTEPS * 2048 * 8);

  for (int kk = 0; kk < KSTEPS; ++kk) {
    if (kk) __syncthreads();   // previous compute done before LDS overwrite

    // ---- stage X tile: 2048 slots x 16B, swizzled SOURCE, linear LDS dest ----
#pragma unroll
    for (int i = 0; i < 8; ++i) {
      int s   = i * 256 + tid;
      int row = s >> 4;
      int c   = s & 15;
      int srcslot = c ^ (row & 15);
      const float* gp = xg + (size_t)row * XCOLS + kk * BK + srcslot * 4;
      __builtin_amdgcn_global_load_lds(
          (const __attribute__((address_space(1))) void*)gp,
          (__attribute__((address_space(3))) void*)&xs[(i * 256 + wave * 64) * 4],
          16, 0, 0);
    }
    // ---- stage W tile: linear copy of pre-swizzled bf16 ----
    const unsigned short* wk = wbase + kk * (2048 * 8);
#pragma unroll
    for (int i = 0; i < 8; ++i) {
      int s = i * 256 + tid;
      __builtin_amdgcn_global_load_lds(
          (const __attribute__((address_space(1))) void*)(wk + s * 8),
          (__attribute__((address_space(3))) void*)&ws[(i * 256 + wave * 64) * 8],
          16, 0, 0);
    }
    __syncthreads();   // compiler drains vmcnt(0) before s_barrier

    // ---- compute: wave covers rows 0..127, cols wave*64..wave*64+63 ----
#pragma unroll
    for (int ks = 0; ks < 2; ++ks) {
      bf16x8_t bfrag[4];
#pragma unroll
      for (int nf = 0; nf < 4; ++nf) {
        int o    = wave * 64 + nf * 16 + fr;   // output col (W row)
        int slot = ks * 4 + fq;
        int sw   = slot ^ (o & 7);
        bfrag[nf] = *(const bf16x8_t*)&ws[(o * 8 + sw) * 8];
      }
#pragma unroll
      for (int mf = 0; mf < 8; ++mf) {
        int row   = mf * 16 + fr;
        int slot0 = ks * 8 + fq * 2;
        union { f32x4_t f; uint32_t u[4]; } A0, A1;
        A0.f = *(const f32x4_t*)&xs[(row * 16 + ((slot0)     ^ (row & 15))) * 4];
        A1.f = *(const f32x4_t*)&xs[(row * 16 + ((slot0 + 1) ^ (row & 15))) * 4];
        union { uint32_t u[4]; bf16x8_t v; } af;
        af.u[0] = ((A0.u[0] + 0x8000u) >> 16) | ((A0.u[1] + 0x8000u) & 0xFFFF0000u);
        af.u[1] = ((A0.u[2] + 0x8000u) >> 16) | ((A0.u[3] + 0x8000u) & 0xFFFF0000u);
        af.u[2] = ((A1.u[0] + 0x8000u) >> 16) | ((A1.u[1] + 0x8000u) & 0xFFFF0000u);
        af.u[3] = ((A1.u[2] + 0x8000u) >> 16) | ((A1.u[3] + 0x8000u) & 0xFFFF0000u);
#pragma unroll
        for (int nf = 0; nf < 4; ++nf)
          acc[mf][nf] = __builtin_amdgcn_mfma_f32_16x16x32_bf16(
              af.v, bfrag[nf], acc[mf][nf], 0, 0, 0);
      }
    }
  }

  // ---- epilogue: C/D layout col = lane&15, row = (lane>>4)*4 + reg ----
  float bv[4];
#pragma unroll
  for (int nf = 0; nf < 4; ++nf)
    bv[nf] = bias[n * BOUT + wave * 64 + nf * 16 + fr];

  float* yg = y + (size_t)m0 * XCOLS + n * BOUT + wave * 64;
#pragma unroll
  for (int mf = 0; mf < 8; ++mf) {
#pragma unroll
    for (int r = 0; r < 4; ++r) {
      float* yrow = yg + (size_t)(mf * 16 + fq * 4 + r) * XCOLS;
#pragma unroll
      for (int nf = 0; nf < 4; ++nf)
        yrow[nf * 16 + fr] = acc[mf][nf][r] + bv[nf];
    }
  }
}

// ---------------- fallback (ws too small): correct but slow fp32 ----------------
__global__ __launch_bounds__(256) void fallback_kernel(
    const float* __restrict__ x, const float* __restrict__ W,
    const float* __restrict__ b, float* __restrict__ y) {
  __shared__ float xrow[BIN];
  int row = blockIdx.x >> 3;
  int n   = blockIdx.x & 7;
  xrow[threadIdx.x] = x[(size_t)row * XCOLS + n * BIN + threadIdx.x];
  __syncthreads();
  const float* w = W + (size_t)(n * BOUT + threadIdx.x) * BIN;
  float s = b[n * BOUT + threadIdx.x];
  for (int i = 0; i < BIN; ++i) s += xrow[i] * w[i];
  y[(size_t)row * XCOLS + n * BIN + threadIdx.x] = s;
}

extern "C" void kernel_launch(void* const* d_in, const int* in_sizes, int n_in,
                              void* d_out, int out_size, void* d_ws, size_t ws_size,
                              hipStream_t stream) {
  const float* x = (const float*)d_in[0];
  const float* W = (const float*)d_in[1];
  const float* b = (const float*)d_in[2];
  float* y = (float*)d_out;

  const size_t ws_needed = (size_t)NBLK * KSTEPS * 2048 * 8 * sizeof(unsigned short); // 1 MB
  if (ws_size >= ws_needed) {
    unsigned short* Wsz = (unsigned short*)d_ws;
    prep_w_kernel<<<2048, 256, 0, stream>>>(W, Wsz);
    blocklinear_kernel<<<(BATCH / BM) * NBLK, 256, 0, stream>>>(x, Wsz, b, y);
  } else {
    fallback_kernel<<<BATCH * NBLK, 256, 0, stream>>>(x, W, b, y);
  }
}

// Round 2
// 102.330 us; speedup vs baseline: 1.2208x; 1.2208x over previous
//
#include <hip/hip_runtime.h>
#include <hip/hip_bf16.h>
#include <stdint.h>

#define BATCH   32768
#define NBLK    8
#define BIN     256
#define BOUT    256
#define XCOLS   2048      // NBLK*BIN
#define BM      64
#define BK      64
#define KSTEPS  4         // BIN/BK

typedef short bf16x8_t __attribute__((ext_vector_type(8)));
typedef float f32x4_t  __attribute__((ext_vector_type(4)));

// ---------------- prepass: W fp32 [8][256][256] -> swizzled bf16 ws ----------------
// Wsz layout [n][kk][s=o*8+c][j=0..7] (16B slots). The main kernel copies this
// LINEARLY into LDS (global_load_lds), so the XOR swizzle is baked in here:
//   LDS slot (o, c) must hold k-run (c ^ (o&7))*8 of row o, K-tile kk.
__global__ __launch_bounds__(256) void prep_w_kernel(
    const float* __restrict__ W, unsigned short* __restrict__ Wsz) {
  int idx = blockIdx.x * 256 + threadIdx.x;   // 0 .. 2^19-1
  int j  = idx & 7;
  int s  = (idx >> 3) & 2047;
  int kk = (idx >> 14) & 3;
  int n  = idx >> 16;
  int o  = s >> 3;
  int c  = s & 7;
  int k  = kk * 64 + ((c ^ (o & 7)) * 8) + j;
  float v = W[((size_t)(n * 256 + o) * 256) + k];
  uint32_t bits = __builtin_bit_cast(uint32_t, v);
  // round-to-nearest-even
  Wsz[idx] = (unsigned short)((bits + 0x7FFFu + ((bits >> 16) & 1u)) >> 16);
}

// ---------------- main kernel ----------------
__global__ __launch_bounds__(256, 3) void blocklinear_kernel(
    const float* __restrict__ x, const unsigned short* __restrict__ Wsz,
    const float* __restrict__ bias, float* __restrict__ y) {
  // X tile staged as fp32 (converted to bf16 at fragment-read time).
  // 16B-slot XOR swizzle: slot ^= (row & 15)  [16 slots/row of 256B]
  __shared__ __align__(16) float          xs[BM * BK];      // 16 KB
  // W tile bf16, swizzle pre-baked by prepass: slot ^= (o & 7) [8 slots/row]
  __shared__ __align__(16) unsigned short ws[BOUT * BK];    // 32 KB

  const int wgid = blockIdx.x;
  const int n    = wgid & 7;        // block id fastest -> per-XCD W L2 affinity
  const int mt   = wgid >> 3;
  const int m0   = mt * BM;
  const int tid  = threadIdx.x;
  const int wave = tid >> 6;
  const int lane = tid & 63;
  const int fr   = lane & 15;
  const int fq   = lane >> 4;

  f32x4_t acc[4][4];
#pragma unroll
  for (int mf = 0; mf < 4; ++mf)
#pragma unroll
    for (int nf = 0; nf < 4; ++nf)
      acc[mf][nf] = (f32x4_t){0.f, 0.f, 0.f, 0.f};

  const float* xg = x + (size_t)m0 * XCOLS + n * BIN;
  const unsigned short* wbase = Wsz + (size_t)n * (KSTEPS * 2048 * 8);

  for (int kk = 0; kk < KSTEPS; ++kk) {
    if (kk) __syncthreads();   // previous compute done before LDS overwrite

    // ---- stage X tile: 1024 slots x 16B, swizzled SOURCE, linear LDS dest ----
#pragma unroll
    for (int i = 0; i < 4; ++i) {
      int s   = i * 256 + tid;
      int row = s >> 4;
      int c   = s & 15;
      int srcslot = c ^ (row & 15);
      const float* gp = xg + (size_t)row * XCOLS + kk * BK + srcslot * 4;
      __builtin_amdgcn_global_load_lds(
          (const __attribute__((address_space(1))) void*)gp,
          (__attribute__((address_space(3))) void*)&xs[(i * 256 + wave * 64) * 4],
          16, 0, 0);
    }
    // ---- stage W tile: 2048 slots x 16B, linear copy of pre-swizzled bf16 ----
    const unsigned short* wk = wbase + kk * (2048 * 8);
#pragma unroll
    for (int i = 0; i < 8; ++i) {
      int s = i * 256 + tid;
      __builtin_amdgcn_global_load_lds(
          (const __attribute__((address_space(1))) void*)(wk + s * 8),
          (__attribute__((address_space(3))) void*)&ws[(i * 256 + wave * 64) * 8],
          16, 0, 0);
    }
    __syncthreads();   // compiler drains vmcnt(0) before s_barrier

    // ---- compute: wave covers rows 0..63, cols wave*64..wave*64+63 ----
#pragma unroll
    for (int ks = 0; ks < 2; ++ks) {
      bf16x8_t bfrag[4];
#pragma unroll
      for (int nf = 0; nf < 4; ++nf) {
        int o    = wave * 64 + nf * 16 + fr;   // output col (W row)
        int slot = ks * 4 + fq;
        int sw   = slot ^ (o & 7);
        bfrag[nf] = *(const bf16x8_t*)&ws[(o * 8 + sw) * 8];
      }
#pragma unroll
      for (int mf = 0; mf < 4; ++mf) {
        int row   = mf * 16 + fr;
        int slot0 = ks * 8 + fq * 2;
        union { f32x4_t f; uint32_t u[4]; } A0, A1;
        A0.f = *(const f32x4_t*)&xs[(row * 16 + ((slot0)     ^ (row & 15))) * 4];
        A1.f = *(const f32x4_t*)&xs[(row * 16 + ((slot0 + 1) ^ (row & 15))) * 4];
        union { uint32_t u[4]; bf16x8_t v; } af;
        af.u[0] = ((A0.u[0] + 0x8000u) >> 16) | ((A0.u[1] + 0x8000u) & 0xFFFF0000u);
        af.u[1] = ((A0.u[2] + 0x8000u) >> 16) | ((A0.u[3] + 0x8000u) & 0xFFFF0000u);
        af.u[2] = ((A1.u[0] + 0x8000u) >> 16) | ((A1.u[1] + 0x8000u) & 0xFFFF0000u);
        af.u[3] = ((A1.u[2] + 0x8000u) >> 16) | ((A1.u[3] + 0x8000u) & 0xFFFF0000u);
#pragma unroll
        for (int nf = 0; nf < 4; ++nf)
          acc[mf][nf] = __builtin_amdgcn_mfma_f32_16x16x32_bf16(
              af.v, bfrag[nf], acc[mf][nf], 0, 0, 0);
      }
    }
  }

  // ---- epilogue: C/D layout col = lane&15, row = (lane>>4)*4 + reg ----
  float bv[4];
#pragma unroll
  for (int nf = 0; nf < 4; ++nf)
    bv[nf] = bias[n * BOUT + wave * 64 + nf * 16 + fr];

  float* yg = y + (size_t)m0 * XCOLS + n * BOUT + wave * 64;
#pragma unroll
  for (int mf = 0; mf < 4; ++mf) {
#pragma unroll
    for (int r = 0; r < 4; ++r) {
      float* yrow = yg + (size_t)(mf * 16 + fq * 4 + r) * XCOLS;
#pragma unroll
      for (int nf = 0; nf < 4; ++nf)
        __builtin_nontemporal_store(acc[mf][nf][r] + bv[nf], &yrow[nf * 16 + fr]);
    }
  }
}

// ---------------- fallback (ws too small): correct but slow fp32 ----------------
__global__ __launch_bounds__(256) void fallback_kernel(
    const float* __restrict__ x, const float* __restrict__ W,
    const float* __restrict__ b, float* __restrict__ y) {
  __shared__ float xrow[BIN];
  int row = blockIdx.x >> 3;
  int n   = blockIdx.x & 7;
  xrow[threadIdx.x] = x[(size_t)row * XCOLS + n * BIN + threadIdx.x];
  __syncthreads();
  const float* w = W + (size_t)(n * BOUT + threadIdx.x) * BIN;
  float s = b[n * BOUT + threadIdx.x];
  for (int i = 0; i < BIN; ++i) s += xrow[i] * w[i];
  y[(size_t)row * XCOLS + n * BIN + threadIdx.x] = s;
}

extern "C" void kernel_launch(void* const* d_in, const int* in_sizes, int n_in,
                              void* d_out, int out_size, void* d_ws, size_t ws_size,
                              hipStream_t stream) {
  const float* x = (const float*)d_in[0];
  const float* W = (const float*)d_in[1];
  const float* b = (const float*)d_in[2];
  float* y = (float*)d_out;

  const size_t ws_needed = (size_t)NBLK * KSTEPS * 2048 * 8 * sizeof(unsigned short); // 1 MB
  if (ws_size >= ws_needed) {
    unsigned short* Wsz = (unsigned short*)d_ws;
    prep_w_kernel<<<2048, 256, 0, stream>>>(W, Wsz);
    blocklinear_kernel<<<(BATCH / BM) * NBLK, 256, 0, stream>>>(x, Wsz, b, y);
  } else {
    fallback_kernel<<<BATCH * NBLK, 256, 0, stream>>>(x, W, b, y);
  }
}